// Round 2
// baseline (1518.725 us; speedup 1.0000x reference)
//
#include <hip/hip_runtime.h>
#include <hip/hip_bf16.h>
#include <math.h>

// Problem constants
#define BB   2
#define TT   256
#define DD   256
#define HH   4
#define NN   32768
#define nn   8192
#define VV   32000
#define L_LAYERS 6
#define LN_EPS 1e-5f

typedef __attribute__((ext_vector_type(8))) short bf16x8;
typedef __attribute__((ext_vector_type(4))) float f32x4;

__device__ __forceinline__ unsigned short f2bf(float f) {
    union { float f; unsigned int u; } v; v.f = f;
    unsigned int r = (v.u + 0x7FFFu + ((v.u >> 16) & 1u)) >> 16;
    return (unsigned short)r;
}
__device__ __forceinline__ float bf2f(unsigned short h) {
    union { unsigned int u; float f; } v; v.u = ((unsigned int)h) << 16;
    return v.f;
}
// 16B load -> bf16x8 (works for global or LDS pointers)
__device__ __forceinline__ bf16x8 ld_frag16(const unsigned short* p) {
    union { bf16x8 v; uint4 u; } r;
    r.u = *(const uint4*)p;
    return r.v;
}
__device__ __forceinline__ bf16x8 ld_frag(const unsigned short* p) {
    union { bf16x8 v; uint2 u[2]; } r;
    r.u[0] = *(const uint2*)(p);
    r.u[1] = *(const uint2*)(p + 4);
    return r.v;
}

// ---------------- block reduction helpers (256 threads = 4 waves) ----------------
__device__ __forceinline__ float block_sum(float v) {
    __shared__ float sh[4];
    #pragma unroll
    for (int o = 32; o > 0; o >>= 1) v += __shfl_down(v, o, 64);
    __syncthreads();
    if ((threadIdx.x & 63) == 0) sh[threadIdx.x >> 6] = v;
    __syncthreads();
    return sh[0] + sh[1] + sh[2] + sh[3];
}
__device__ __forceinline__ float block_max(float v) {
    __shared__ float sh[4];
    #pragma unroll
    for (int o = 32; o > 0; o >>= 1) v = fmaxf(v, __shfl_down(v, o, 64));
    __syncthreads();
    if ((threadIdx.x & 63) == 0) sh[threadIdx.x >> 6] = v;
    __syncthreads();
    return fmaxf(fmaxf(sh[0], sh[1]), fmaxf(sh[2], sh[3]));
}
__device__ __forceinline__ float ln_val(float x) {
    float m = block_sum(x) * (1.0f / 256.0f);
    float d = x - m;
    float var = block_sum(d * d) * (1.0f / 256.0f);
    return d * rsqrtf(var + LN_EPS);
}

// ---------------- small row kernels ----------------
__global__ __launch_bounds__(256) void embed_ln_k(const int* __restrict__ idx,
                                                  const float* __restrict__ wte,
                                                  float* __restrict__ v,
                                                  unsigned short* __restrict__ vb) {
    int row = blockIdx.x;
    int tok = idx[row];
    float x = wte[(size_t)tok * DD + threadIdx.x];
    float o = ln_val(x);
    size_t i = (size_t)row * DD + threadIdx.x;
    v[i] = o;
    vb[i] = f2bf(o);
}

__global__ __launch_bounds__(256) void ln_rows_k(const float* __restrict__ in,
                                                 unsigned short* __restrict__ ob) {
    size_t i = (size_t)blockIdx.x * DD + threadIdx.x;
    ob[i] = f2bf(ln_val(in[i]));
}

__global__ __launch_bounds__(256) void add_ln_ln_k(float* __restrict__ v,
                                                   const float* __restrict__ yenc,
                                                   unsigned short* __restrict__ vb) {
    size_t i = (size_t)blockIdx.x * DD + threadIdx.x;
    float t1 = ln_val(yenc[i]);
    float w = v[i] + t1;
    float o = ln_val(w);
    v[i] = o;
    vb[i] = f2bf(o);
}

// ---------------- transpose+convert: dst[c][r] bf16 = src[r][c] fp32 ----------------
__global__ __launch_bounds__(256) void tconv_k(const float* __restrict__ src,
                                               unsigned short* __restrict__ dst,
                                               int R, int C, long sstride, long dstride) {
    src += (size_t)blockIdx.z * sstride;
    dst += (size_t)blockIdx.z * dstride;
    __shared__ unsigned short tile[64][66];
    int c0 = blockIdx.x * 64, r0 = blockIdx.y * 64;
    int c = threadIdx.x & 63, q = threadIdx.x >> 6;
    #pragma unroll
    for (int i = 0; i < 16; i++) {
        int r = q + i * 4;
        tile[r][c] = f2bf(src[(size_t)(r0 + r) * C + c0 + c]);
    }
    __syncthreads();
    #pragma unroll
    for (int i = 0; i < 16; i++) {
        int r = q + i * 4;
        dst[(size_t)(c0 + r) * R + r0 + c] = tile[c][r];
    }
}

// ---------------- RoPE on bf16: xrb = rope(xb), (B,H,T,n) ----------------
__global__ __launch_bounds__(256) void rope_b_k(const unsigned short* __restrict__ xb,
                                                unsigned short* __restrict__ xrb) {
    int gid = blockIdx.x * 256 + threadIdx.x;    // B*H*T*n/8 = 2,097,152
    int grp = gid & 1023;                         // group of 8 shorts (4 pairs)
    int t = (gid >> 10) & 255;
    size_t base = (size_t)(gid >> 10) * nn + grp * 8;
    union { uint4 u; unsigned short s[8]; } xin, xout;
    xin.u = *(const uint4*)(xb + base);
    float tf = (float)t;
    #pragma unroll
    for (int j = 0; j < 4; j++) {
        int p = grp * 4 + j;
        float inv = __expf(-(float)p * (9.210340371976184f / 4096.0f));
        float ang = tf * inv;
        float s = __sinf(ang), c = __cosf(ang);
        float xe = bf2f(xin.s[2 * j]), xo = bf2f(xin.s[2 * j + 1]);
        xout.s[2 * j]     = f2bf(xe * c - xo * s);
        xout.s[2 * j + 1] = f2bf(xo * c + xe * s);
    }
    *(uint4*)(xrb + base) = xout.u;
}

// ======================================================================
// Direct-from-global register GEMM main loop for SMALL-K (K=256) GEMMs.
// No LDS, no barriers. Operands are cache-resident (A=256KB, B<=16.7MB),
// so LDS staging is pure overhead here (cdna guide Common-mistake #7).
// Each wave computes 64x64 via 4x4 16x16x32 MFMA frags, 2-deep reg pipeline.
// Ab points at A row (m0+rowoff+fr), col fq; Bb at B row (n0+coloff+fr), col fq.
// ======================================================================
__device__ __forceinline__ void ldk_reg(const unsigned short* Ab,
                                        const unsigned short* Bb, int k,
                                        bf16x8 (&af)[4], bf16x8 (&bfv)[4]) {
    #pragma unroll
    for (int mi = 0; mi < 4; mi++) af[mi]  = ld_frag16(Ab + (size_t)mi * 16 * DD + k * 32);
    #pragma unroll
    for (int nj = 0; nj < 4; nj++) bfv[nj] = ld_frag16(Bb + (size_t)nj * 16 * DD + k * 32);
}
__device__ __forceinline__ void reg_mainloop_k256(const unsigned short* Ab,
                                                  const unsigned short* Bb,
                                                  f32x4 (&acc)[4][4]) {
    bf16x8 afA[4], bfA[4], afB[4], bfB[4];
    ldk_reg(Ab, Bb, 0, afA, bfA);
    ldk_reg(Ab, Bb, 1, afB, bfB);
    #pragma unroll
    for (int k = 0; k < 8; k += 2) {
        #pragma unroll
        for (int mi = 0; mi < 4; mi++)
            #pragma unroll
            for (int nj = 0; nj < 4; nj++)
                acc[mi][nj] = __builtin_amdgcn_mfma_f32_16x16x32_bf16(afA[mi], bfA[nj], acc[mi][nj], 0, 0, 0);
        if (k + 2 < 8) ldk_reg(Ab, Bb, k + 2, afA, bfA);
        #pragma unroll
        for (int mi = 0; mi < 4; mi++)
            #pragma unroll
            for (int nj = 0; nj < 4; nj++)
                acc[mi][nj] = __builtin_amdgcn_mfma_f32_16x16x32_bf16(afB[mi], bfB[nj], acc[mi][nj], 0, 0, 0);
        if (k + 3 < 8) ldk_reg(Ab, Bb, k + 3, afB, bfB);
    }
}

// ---------------- head GEMM: relu(vb @ WxT[h]) -> xb (mode 0) / y path (mode 1) -------
__global__ __launch_bounds__(256) void gemm_head_bt(const unsigned short* __restrict__ A,
                                                    const unsigned short* __restrict__ Wt,
                                                    unsigned short* __restrict__ Cx,
                                                    const unsigned short* __restrict__ mulx,
                                                    unsigned short* __restrict__ Cy,
                                                    int mode) {
    int h = blockIdx.z;
    int n0 = blockIdx.x * 128, m0 = blockIdx.y * 128;
    int tid = threadIdx.x, lane = tid & 63, w = tid >> 6;
    int rowoff = (w >> 1) * 64, coloff = (w & 1) * 64;
    int fr = lane & 15, fq = (lane >> 4) * 8;
    const unsigned short* Ab = A + (size_t)(m0 + rowoff + fr) * DD + fq;
    const unsigned short* Bb = Wt + (size_t)h * nn * DD + (size_t)(n0 + coloff + fr) * DD + fq;
    f32x4 acc[4][4] = {};
    reg_mainloop_k256(Ab, Bb, acc);
    int r4 = (lane >> 4) * 4, cc = lane & 15;
    #pragma unroll
    for (int mi = 0; mi < 4; mi++)
        #pragma unroll
        for (int nj = 0; nj < 4; nj++)
            #pragma unroll
            for (int rr = 0; rr < 4; rr++) {
                int m = m0 + rowoff + mi * 16 + r4 + rr;
                int col = n0 + coloff + nj * 16 + cc;
                float cv = fmaxf(acc[mi][nj][rr], 0.0f);
                int b = m >> 8, t = m & 255;
                size_t bhtn = (((size_t)(b * HH + h)) * TT + t) * (size_t)nn + col;
                if (mode == 0) {
                    Cx[bhtn] = f2bf(cv);
                } else {
                    cv *= bf2f(mulx[bhtn]);
                    Cy[((size_t)(b * TT + t)) * NN + (size_t)h * nn + col] = f2bf(cv);
                }
            }
}

// ---------------- readout: out = vb @ WroT^T, fp32 out (direct-global, K=256) ---------
__global__ __launch_bounds__(256) void gemm_ro_bt(const unsigned short* __restrict__ A,
                                                  const unsigned short* __restrict__ Wt,
                                                  float* __restrict__ out) {
    int n0 = blockIdx.x * 128, m0 = blockIdx.y * 128;
    int tid = threadIdx.x, lane = tid & 63, w = tid >> 6;
    int rowoff = (w >> 1) * 64, coloff = (w & 1) * 64;
    int fr = lane & 15, fq = (lane >> 4) * 8;
    const unsigned short* Ab = A + (size_t)(m0 + rowoff + fr) * DD + fq;
    const unsigned short* Bb = Wt + (size_t)(n0 + coloff + fr) * DD + fq;
    f32x4 acc[4][4] = {};
    reg_mainloop_k256(Ab, Bb, acc);
    int r4 = (lane >> 4) * 4, cc = lane & 15;
    #pragma unroll
    for (int mi = 0; mi < 4; mi++)
        #pragma unroll
        for (int nj = 0; nj < 4; nj++)
            #pragma unroll
            for (int rr = 0; rr < 4; rr++) {
                int m = m0 + rowoff + mi * 16 + r4 + rr;
                int col = n0 + coloff + nj * 16 + cc;
                out[(size_t)m * VV + col] = acc[mi][nj][rr];
            }
}

// ======================================================================
// LDS-staged BT-GEMM main loop (reg-staged, pipelined) — for LARGE-K GEMMs
// (scores K=8192, encoder K=32768). R0-verified structure.
// ======================================================================
__device__ __forceinline__ void bt_mainloop(const unsigned short* Ap, long lda,
                                            const unsigned short* Bp, long ldb,
                                            int ksteps,
                                            unsigned short (*As)[36],
                                            unsigned short (*Bs)[36],
                                            f32x4 (&acc)[4][4]) {
    int tid = threadIdx.x;
    int ra = tid >> 1, pa = (tid & 1) * 16;
    int lane = tid & 63, w = tid >> 6;
    int rowoff = (w >> 1) * 64, coloff = (w & 1) * 64;
    int fr = lane & 15, fq = (lane >> 4) * 8;
    const unsigned short* ga = Ap + (size_t)ra * lda + pa;
    const unsigned short* gb = Bp + (size_t)ra * ldb + pa;
    uint4 a0 = *(const uint4*)ga, a1 = *(const uint4*)(ga + 8);
    uint4 b0 = *(const uint4*)gb, b1 = *(const uint4*)(gb + 8);
    for (int k = 0; k < ksteps; k++) {
        __syncthreads();
        uint2* da = (uint2*)&As[ra][pa];
        da[0] = make_uint2(a0.x, a0.y); da[1] = make_uint2(a0.z, a0.w);
        da[2] = make_uint2(a1.x, a1.y); da[3] = make_uint2(a1.z, a1.w);
        uint2* db = (uint2*)&Bs[ra][pa];
        db[0] = make_uint2(b0.x, b0.y); db[1] = make_uint2(b0.z, b0.w);
        db[2] = make_uint2(b1.x, b1.y); db[3] = make_uint2(b1.z, b1.w);
        if (k + 1 < ksteps) {
            ga += 32; gb += 32;
            a0 = *(const uint4*)ga; a1 = *(const uint4*)(ga + 8);
            b0 = *(const uint4*)gb; b1 = *(const uint4*)(gb + 8);
        }
        __syncthreads();
        bf16x8 af[4], bfv[4];
        #pragma unroll
        for (int mi = 0; mi < 4; mi++) af[mi] = ld_frag(&As[rowoff + mi * 16 + fr][fq]);
        #pragma unroll
        for (int nj = 0; nj < 4; nj++) bfv[nj] = ld_frag(&Bs[coloff + nj * 16 + fr][fq]);
        #pragma unroll
        for (int mi = 0; mi < 4; mi++)
            #pragma unroll
            for (int nj = 0; nj < 4; nj++)
                acc[mi][nj] = __builtin_amdgcn_mfma_f32_16x16x32_bf16(af[mi], bfv[nj], acc[mi][nj], 0, 0, 0);
    }
}

// ---------------- scores: sc += scale * xrb @ xrb^T (split-K 16, causal tiles) --------
__global__ __launch_bounds__(256) void scores_bt(const unsigned short* __restrict__ xrb,
                                                 float* __restrict__ sc) {
    int zh = blockIdx.z, kc = blockIdx.y, tile = blockIdx.x;
    int t0 = (tile >= 1) ? 128 : 0;
    int s0 = (tile == 2) ? 128 : 0;
    const unsigned short* Xz = xrb + (size_t)zh * TT * nn + (size_t)kc * 512;
    __shared__ unsigned short As[128][36], Bs[128][36];
    f32x4 acc[4][4] = {};
    bt_mainloop(Xz + (size_t)t0 * nn, nn, Xz + (size_t)s0 * nn, nn, 16, As, Bs, acc);
    const float scale = 0.011048543456039805f;   // 1/sqrt(8192)
    int tid = threadIdx.x, lane = tid & 63, w = tid >> 6;
    int rowoff = (w >> 1) * 64, coloff = (w & 1) * 64;
    int r4 = (lane >> 4) * 4, cc = lane & 15;
    float* scz = sc + (size_t)zh * TT * TT;
    #pragma unroll
    for (int mi = 0; mi < 4; mi++)
        #pragma unroll
        for (int nj = 0; nj < 4; nj++)
            #pragma unroll
            for (int rr = 0; rr < 4; rr++) {
                int t = t0 + rowoff + mi * 16 + r4 + rr;
                int s = s0 + coloff + nj * 16 + cc;
                atomicAdd(&scz[(size_t)t * TT + s], acc[mi][nj][rr] * scale);
            }
}

// ---------------- encoder GEMM: yenc += ybf(512x32768) @ encT^T (split-K 32) ----------
__global__ __launch_bounds__(256) void gemm_enc_bt(const unsigned short* __restrict__ A,
                                                   const unsigned short* __restrict__ Bt,
                                                   float* __restrict__ C) {
    int n0 = blockIdx.x * 128, m0 = blockIdx.y * 128;
    long kbase = (long)blockIdx.z * 1024;
    __shared__ unsigned short As[128][36], Bs[128][36];
    f32x4 acc[4][4] = {};
    bt_mainloop(A + (size_t)m0 * NN + kbase, NN,
                Bt + (size_t)n0 * NN + kbase, NN, 32, As, Bs, acc);
    int tid = threadIdx.x, lane = tid & 63, w = tid >> 6;
    int rowoff = (w >> 1) * 64, coloff = (w & 1) * 64;
    int r4 = (lane >> 4) * 4, cc = lane & 15;
    #pragma unroll
    for (int mi = 0; mi < 4; mi++)
        #pragma unroll
        for (int nj = 0; nj < 4; nj++)
            #pragma unroll
            for (int rr = 0; rr < 4; rr++) {
                int row = m0 + rowoff + mi * 16 + r4 + rr;
                int col = n0 + coloff + nj * 16 + cc;
                atomicAdd(&C[(size_t)row * DD + col], acc[mi][nj][rr]);
            }
}

// ---------------- causal softmax per (b,h,t) + mean over h -> am (B,T,T) ----------------
__global__ __launch_bounds__(256) void softmax_mean_k(const float* __restrict__ sc,
                                                      float* __restrict__ am) {
    int bt = blockIdx.x;
    int b = bt >> 8, t = bt & 255;
    int s = threadIdx.x;
    float acc = 0.0f;
    for (int h = 0; h < HH; h++) {
        const float* row = sc + (((size_t)(b * HH + h)) * TT + t) * TT;
        float val = (s <= t) ? row[s] : -1e30f;
        float mx = block_max(val);
        float e = (s <= t) ? expf(val - mx) : 0.0f;
        float sum = block_sum(e);
        acc += e / sum;
    }
    am[((size_t)b * TT + t) * TT + s] = acc * 0.25f;
}

// ---------------- fp32 NN GEMM — used only for a = am @ v ----------------
__global__ __launch_bounds__(256) void gemm_nn_k(const float* __restrict__ A,
                                                 const float* __restrict__ B,
                                                 float* __restrict__ C,
                                                 int M, int N, int K,
                                                 long lda, long ldb, long ldc,
                                                 long sAz, long sBz, long sCz) {
    int batch = blockIdx.z;
    A += (size_t)batch * sAz;
    B += (size_t)batch * sBz;
    C += (size_t)batch * sCz;
    int m0 = blockIdx.y * 64, n0 = blockIdx.x * 64;
    __shared__ float As[16][68];
    __shared__ float Bs[16][64];
    int tid = threadIdx.x;
    int tx = tid & 15, ty = tid >> 4;
    int ar = tid >> 2, ac = (tid & 3) * 4;
    int br = tid >> 4, bc = (tid & 15) * 4;
    float acc[4][4] = {};
    for (int k0 = 0; k0 < K; k0 += 16) {
        float4 av = *(const float4*)(A + (size_t)(m0 + ar) * lda + k0 + ac);
        float4 bv = *(const float4*)(B + (size_t)(k0 + br) * ldb + n0 + bc);
        As[ac + 0][ar] = av.x; As[ac + 1][ar] = av.y;
        As[ac + 2][ar] = av.z; As[ac + 3][ar] = av.w;
        *(float4*)&Bs[br][bc] = bv;
        __syncthreads();
        #pragma unroll
        for (int k = 0; k < 16; k++) {
            float4 a4 = *(const float4*)&As[k][ty * 4];
            float4 b4 = *(const float4*)&Bs[k][tx * 4];
            float aa[4] = {a4.x, a4.y, a4.z, a4.w};
            float bb[4] = {b4.x, b4.y, b4.z, b4.w};
            #pragma unroll
            for (int i = 0; i < 4; i++)
                #pragma unroll
                for (int j = 0; j < 4; j++)
                    acc[i][j] = fmaf(aa[i], bb[j], acc[i][j]);
        }
        __syncthreads();
    }
    #pragma unroll
    for (int i = 0; i < 4; i++) {
        int m = m0 + ty * 4 + i;
        #pragma unroll
        for (int j = 0; j < 4; j++) {
            int col = n0 + tx * 4 + j;
            C[(size_t)m * ldc + col] = acc[i][j];
        }
    }
}

// ---------------- launch ----------------
extern "C" void kernel_launch(void* const* d_in, const int* in_sizes, int n_in,
                              void* d_out, int out_size, void* d_ws, size_t ws_size,
                              hipStream_t stream) {
    const int*   idx  = (const int*)d_in[0];
    const float* wte  = (const float*)d_in[1];
    const float* enc  = (const float*)d_in[2];
    const float* Wx   = (const float*)d_in[3];
    const float* Wy   = (const float*)d_in[4];
    const float* Wro  = (const float*)d_in[5];
    float* out = (float*)d_out;

    // float region (1,048,576 floats = 4 MB)
    float* ws   = (float*)d_ws;
    float* v    = ws;                  // 131072
    float* sc   = v    + 131072;       // 524288
    float* am   = sc   + 524288;       // 131072
    float* a    = am   + 131072;       // 131072
    float* yenc = a    + 131072;       // 131072
    // short region
    unsigned short* sbase = (unsigned short*)(yenc + 131072);
    unsigned short* vb   = sbase;                 // 131072
    unsigned short* lAb  = vb   + 131072;         // 131072
    unsigned short* xb   = lAb  + 131072;         // 16777216 (B,H,T,n); WroT aliases at end
    unsigned short* xrb  = xb   + 16777216;       // 16777216 (B,H,T,n); ybf aliases
    unsigned short* WxT  = xrb  + 16777216;       // 8388608  [h][8192][256]
    unsigned short* WyT  = WxT  + 8388608;        // 8388608
    unsigned short* encT = WyT  + 8388608;        // 8388608  [256][32768]
    unsigned short* ybf  = xrb;                   // alias: xrb dead after scores
    unsigned short* WroT = xb;                    // alias: xb dead after last y-GEMM

    // pre-pass: weight transpose+convert (once per launch, amortized over 6 layers)
    tconv_k<<<dim3(nn / 64, DD / 64, HH), 256, 0, stream>>>(Wx, WxT, DD, nn,
        (long)DD * nn, (long)nn * DD);
    tconv_k<<<dim3(DD / 64, NN / 64, 1), 256, 0, stream>>>(enc, encT, NN, DD, 0L, 0L);
    tconv_k<<<dim3(nn / 64, DD / 64, HH), 256, 0, stream>>>(Wy, WyT, DD, nn,
        (long)DD * nn, (long)nn * DD);

    // v = ln(wte[idx]) (+ bf16)
    embed_ln_k<<<BB * TT, 256, 0, stream>>>(idx, wte, v, vb);

    for (int l = 0; l < L_LAYERS; l++) {
        // xb = bf16(relu(vb @ WxT[h]))
        gemm_head_bt<<<dim3(nn / 128, (BB * TT) / 128, HH), 256, 0, stream>>>(
            vb, WxT, xb, nullptr, nullptr, 0);

        // xrb = rope(xb)
        rope_b_k<<<(BB * HH * TT * nn / 8) / 256, 256, 0, stream>>>(xb, xrb);

        // sc = scale * xrb @ xrb^T (split-K 16, causal tiles)
        hipMemsetAsync(sc, 0, (size_t)524288 * sizeof(float), stream);
        scores_bt<<<dim3(3, 16, BB * HH), 256, 0, stream>>>(xrb, sc);

        // softmax (causal) + mean over heads
        softmax_mean_k<<<BB * TT, 256, 0, stream>>>(sc, am);

        // a = am @ v (per b), fp32
        gemm_nn_k<<<dim3(DD / 64, TT / 64, BB), 256, 0, stream>>>(
            am, v, a, TT, DD, TT,
            (long)TT, (long)DD, (long)DD,
            (long)TT * TT, (long)TT * DD, (long)TT * DD);

        // lAb = bf16(ln(a))
        ln_rows_k<<<BB * TT, 256, 0, stream>>>(a, lAb);

        // ybf = bf16(relu(lAb @ WyT[h]) * xb)   (ybf aliases xrb)
        gemm_head_bt<<<dim3(nn / 128, (BB * TT) / 128, HH), 256, 0, stream>>>(
            lAb, WyT, nullptr, xb, ybf, 1);

        // yenc = ybf @ enc (split-K 32)
        hipMemsetAsync(yenc, 0, (size_t)131072 * sizeof(float), stream);
        gemm_enc_bt<<<dim3(2, 4, 32), 256, 0, stream>>>(ybf, encT, yenc);

        // v = ln(v + ln(yenc)) (+ bf16)
        add_ln_ln_k<<<BB * TT, 256, 0, stream>>>(v, yenc, vb);
    }

    // WroT = transpose+bf16(Wro) into xb region (xb dead now)
    tconv_k<<<dim3(VV / 64, DD / 64, 1), 256, 0, stream>>>(Wro, WroT, DD, VV, 0L, 0L);

    // out = vb @ WroT^T (fp32 out)
    gemm_ro_bt<<<dim3(VV / 128, (BB * TT) / 128, 1), 256, 0, stream>>>(vb, WroT, out);
}

// Round 3
// 1120.990 us; speedup vs baseline: 1.3548x; 1.3548x over previous
//
#include <hip/hip_runtime.h>
#include <hip/hip_bf16.h>
#include <math.h>

// Problem constants
#define BB   2
#define TT   256
#define DD   256
#define HH   4
#define NN   32768
#define nn   8192
#define VV   32000
#define L_LAYERS 6
#define LN_EPS 1e-5f

typedef __attribute__((ext_vector_type(8))) short bf16x8;
typedef __attribute__((ext_vector_type(4))) float f32x4;

__device__ __forceinline__ unsigned short f2bf(float f) {
    union { float f; unsigned int u; } v; v.f = f;
    unsigned int r = (v.u + 0x7FFFu + ((v.u >> 16) & 1u)) >> 16;
    return (unsigned short)r;
}
__device__ __forceinline__ float bf2f(unsigned short h) {
    union { unsigned int u; float f; } v; v.u = ((unsigned int)h) << 16;
    return v.f;
}
__device__ __forceinline__ bf16x8 ld_frag(const unsigned short* p) {
    union { bf16x8 v; uint2 u[2]; } r;
    r.u[0] = *(const uint2*)(p);
    r.u[1] = *(const uint2*)(p + 4);
    return r.v;
}

// ---------------- block reduction helpers (256 threads = 4 waves) ----------------
__device__ __forceinline__ float block_sum(float v) {
    __shared__ float sh[4];
    #pragma unroll
    for (int o = 32; o > 0; o >>= 1) v += __shfl_down(v, o, 64);
    __syncthreads();
    if ((threadIdx.x & 63) == 0) sh[threadIdx.x >> 6] = v;
    __syncthreads();
    return sh[0] + sh[1] + sh[2] + sh[3];
}
__device__ __forceinline__ float block_max(float v) {
    __shared__ float sh[4];
    #pragma unroll
    for (int o = 32; o > 0; o >>= 1) v = fmaxf(v, __shfl_down(v, o, 64));
    __syncthreads();
    if ((threadIdx.x & 63) == 0) sh[threadIdx.x >> 6] = v;
    __syncthreads();
    return fmaxf(fmaxf(sh[0], sh[1]), fmaxf(sh[2], sh[3]));
}
__device__ __forceinline__ float ln_val(float x) {
    float m = block_sum(x) * (1.0f / 256.0f);
    float d = x - m;
    float var = block_sum(d * d) * (1.0f / 256.0f);
    return d * rsqrtf(var + LN_EPS);
}

// ---------------- small row kernels ----------------
__global__ __launch_bounds__(256) void embed_ln_k(const int* __restrict__ idx,
                                                  const float* __restrict__ wte,
                                                  float* __restrict__ v,
                                                  unsigned short* __restrict__ vb) {
    int row = blockIdx.x;
    int tok = idx[row];
    float x = wte[(size_t)tok * DD + threadIdx.x];
    float o = ln_val(x);
    size_t i = (size_t)row * DD + threadIdx.x;
    v[i] = o;
    vb[i] = f2bf(o);
}

__global__ __launch_bounds__(256) void ln_rows_k(const float* __restrict__ in,
                                                 unsigned short* __restrict__ ob) {
    size_t i = (size_t)blockIdx.x * DD + threadIdx.x;
    ob[i] = f2bf(ln_val(in[i]));
}

__global__ __launch_bounds__(256) void add_ln_ln_k(float* __restrict__ v,
                                                   const float* __restrict__ yenc,
                                                   unsigned short* __restrict__ vb) {
    size_t i = (size_t)blockIdx.x * DD + threadIdx.x;
    float t1 = ln_val(yenc[i]);
    float w = v[i] + t1;
    float o = ln_val(w);
    v[i] = o;
    vb[i] = f2bf(o);
}

// ---------------- transpose+convert: dst[c][r] bf16 = src[r][c] fp32 ----------------
__global__ __launch_bounds__(256) void tconv_k(const float* __restrict__ src,
                                               unsigned short* __restrict__ dst,
                                               int R, int C, long sstride, long dstride) {
    src += (size_t)blockIdx.z * sstride;
    dst += (size_t)blockIdx.z * dstride;
    __shared__ unsigned short tile[64][66];
    int c0 = blockIdx.x * 64, r0 = blockIdx.y * 64;
    int c = threadIdx.x & 63, q = threadIdx.x >> 6;
    #pragma unroll
    for (int i = 0; i < 16; i++) {
        int r = q + i * 4;
        tile[r][c] = f2bf(src[(size_t)(r0 + r) * C + c0 + c]);
    }
    __syncthreads();
    #pragma unroll
    for (int i = 0; i < 16; i++) {
        int r = q + i * 4;
        dst[(size_t)(c0 + r) * R + r0 + c] = tile[c][r];
    }
}

// ======================================================================
// LDS-staged BT-GEMM main loop (reg-staged, pipelined) — R0-verified, 49 µs class.
// Block tile 128x128, 4 waves, each wave 64x64 via 4x4 16x16x32 MFMA frags.
// ======================================================================
__device__ __forceinline__ void bt_mainloop(const unsigned short* Ap, long lda,
                                            const unsigned short* Bp, long ldb,
                                            int ksteps,
                                            unsigned short (*As)[36],
                                            unsigned short (*Bs)[36],
                                            f32x4 (&acc)[4][4]) {
    int tid = threadIdx.x;
    int ra = tid >> 1, pa = (tid & 1) * 16;
    int lane = tid & 63, w = tid >> 6;
    int rowoff = (w >> 1) * 64, coloff = (w & 1) * 64;
    int fr = lane & 15, fq = (lane >> 4) * 8;
    const unsigned short* ga = Ap + (size_t)ra * lda + pa;
    const unsigned short* gb = Bp + (size_t)ra * ldb + pa;
    uint4 a0 = *(const uint4*)ga, a1 = *(const uint4*)(ga + 8);
    uint4 b0 = *(const uint4*)gb, b1 = *(const uint4*)(gb + 8);
    for (int k = 0; k < ksteps; k++) {
        __syncthreads();
        uint2* da = (uint2*)&As[ra][pa];
        da[0] = make_uint2(a0.x, a0.y); da[1] = make_uint2(a0.z, a0.w);
        da[2] = make_uint2(a1.x, a1.y); da[3] = make_uint2(a1.z, a1.w);
        uint2* db = (uint2*)&Bs[ra][pa];
        db[0] = make_uint2(b0.x, b0.y); db[1] = make_uint2(b0.z, b0.w);
        db[2] = make_uint2(b1.x, b1.y); db[3] = make_uint2(b1.z, b1.w);
        if (k + 1 < ksteps) {
            ga += 32; gb += 32;
            a0 = *(const uint4*)ga; a1 = *(const uint4*)(ga + 8);
            b0 = *(const uint4*)gb; b1 = *(const uint4*)(gb + 8);
        }
        __syncthreads();
        bf16x8 af[4], bfv[4];
        #pragma unroll
        for (int mi = 0; mi < 4; mi++) af[mi] = ld_frag(&As[rowoff + mi * 16 + fr][fq]);
        #pragma unroll
        for (int nj = 0; nj < 4; nj++) bfv[nj] = ld_frag(&Bs[coloff + nj * 16 + fr][fq]);
        #pragma unroll
        for (int mi = 0; mi < 4; mi++)
            #pragma unroll
            for (int nj = 0; nj < 4; nj++)
                acc[mi][nj] = __builtin_amdgcn_mfma_f32_16x16x32_bf16(af[mi], bfv[nj], acc[mi][nj], 0, 0, 0);
    }
}

// ---------------- head GEMM with LDS-staged coalesced epilogue ----------------
// mode 0: xb = bf16(relu(vb @ WxT[h])), AND xrb = rope(xb) fused (rope_b_k deleted).
// mode 1: ybf = bf16(relu(lAb @ WyT[h]) * xb), coalesced mulx reads + stores.
__global__ __launch_bounds__(256) void gemm_head_bt(const unsigned short* __restrict__ A,
                                                    const unsigned short* __restrict__ Wt,
                                                    unsigned short* __restrict__ Cx,
                                                    const unsigned short* __restrict__ mulx,
                                                    unsigned short* __restrict__ Cy,
                                                    int mode) {
    int h = blockIdx.z;
    int n0 = blockIdx.x * 128, m0 = blockIdx.y * 128;
    // 32 KB shared: As/Bs (18.4 KB) for mainloop, then re-used as Cs[128][128] bf16.
    __shared__ __attribute__((aligned(16))) unsigned short smem[16384];
    unsigned short (*As)[36] = (unsigned short (*)[36])smem;
    unsigned short (*Bs)[36] = (unsigned short (*)[36])(smem + 128 * 36);
    f32x4 acc[4][4] = {};
    bt_mainloop(A + (size_t)m0 * DD, DD,
                Wt + (size_t)h * nn * DD + (size_t)n0 * DD, DD, 8, As, Bs, acc);
    __syncthreads();   // mainloop done; smem free for output staging

    int tid = threadIdx.x, lane = tid & 63, w = tid >> 6;
    int rowoff = (w >> 1) * 64, coloff = (w & 1) * 64;
    int r4 = (lane >> 4) * 4, cc = lane & 15;
    unsigned short (*Cs)[128] = (unsigned short (*)[128])smem;
    #pragma unroll
    for (int mi = 0; mi < 4; mi++)
        #pragma unroll
        for (int nj = 0; nj < 4; nj++)
            #pragma unroll
            for (int rr = 0; rr < 4; rr++)
                Cs[rowoff + mi * 16 + r4 + rr][coloff + nj * 16 + cc] =
                    f2bf(fmaxf(acc[mi][nj][rr], 0.0f));
    __syncthreads();

    // writer arrangement: thread covers chunks {tid + j*256}, j=0..7.
    // chunk c -> row = c>>4, col = (c&15)*8 (8 shorts = 16 B, coalesced per 16 lanes).
    int colc = (tid & 15) * 8;
    #pragma unroll
    for (int j = 0; j < 8; j++) {
        int row = (tid >> 4) + j * 16;
        int m = m0 + row;
        int b = m >> 8, t = m & 255;
        union { uint4 u; unsigned short s[8]; } ch;
        ch.u = *(const uint4*)&Cs[row][colc];
        if (mode == 0) {
            size_t bhtn = (((size_t)(b * HH + h)) * TT + t) * (size_t)nn + n0 + colc;
            *(uint4*)(Cx + bhtn) = ch.u;                 // xb
            // fused RoPE -> xrb (same math as old rope_b_k, bf16 inputs)
            union { uint4 u; unsigned short s[8]; } ro;
            float tf = (float)t;
            int pbase = ((n0 + colc) >> 1);
            #pragma unroll
            for (int k2 = 0; k2 < 4; k2++) {
                int p = pbase + k2;
                float inv = __expf(-(float)p * (9.210340371976184f / 4096.0f));
                float ang = tf * inv;
                float s = __sinf(ang), c = __cosf(ang);
                float xe = bf2f(ch.s[2 * k2]), xo = bf2f(ch.s[2 * k2 + 1]);
                ro.s[2 * k2]     = f2bf(xe * c - xo * s);
                ro.s[2 * k2 + 1] = f2bf(xo * c + xe * s);
            }
            *(uint4*)(Cy + bhtn) = ro.u;                 // xrb
        } else {
            size_t bhtn = (((size_t)(b * HH + h)) * TT + t) * (size_t)nn + n0 + colc;
            union { uint4 u; unsigned short s[8]; } mx, oy;
            mx.u = *(const uint4*)(mulx + bhtn);
            #pragma unroll
            for (int k2 = 0; k2 < 8; k2++)
                oy.s[k2] = f2bf(bf2f(ch.s[k2]) * bf2f(mx.s[k2]));
            *(uint4*)(Cy + ((size_t)(b * TT + t)) * NN + (size_t)h * nn + n0 + colc) = oy.u;
        }
    }
}

// ---------------- scores: sc += scale * xrb @ xrb^T (split-K 16, causal tiles) --------
__global__ __launch_bounds__(256) void scores_bt(const unsigned short* __restrict__ xrb,
                                                 float* __restrict__ sc) {
    int zh = blockIdx.z, kc = blockIdx.y, tile = blockIdx.x;
    int t0 = (tile >= 1) ? 128 : 0;
    int s0 = (tile == 2) ? 128 : 0;
    const unsigned short* Xz = xrb + (size_t)zh * TT * nn + (size_t)kc * 512;
    __shared__ unsigned short As[128][36], Bs[128][36];
    f32x4 acc[4][4] = {};
    bt_mainloop(Xz + (size_t)t0 * nn, nn, Xz + (size_t)s0 * nn, nn, 16, As, Bs, acc);
    const float scale = 0.011048543456039805f;   // 1/sqrt(8192)
    int tid = threadIdx.x, lane = tid & 63, w = tid >> 6;
    int rowoff = (w >> 1) * 64, coloff = (w & 1) * 64;
    int r4 = (lane >> 4) * 4, cc = lane & 15;
    float* scz = sc + (size_t)zh * TT * TT;
    #pragma unroll
    for (int mi = 0; mi < 4; mi++)
        #pragma unroll
        for (int nj = 0; nj < 4; nj++)
            #pragma unroll
            for (int rr = 0; rr < 4; rr++) {
                int t = t0 + rowoff + mi * 16 + r4 + rr;
                int s = s0 + coloff + nj * 16 + cc;
                atomicAdd(&scz[(size_t)t * TT + s], acc[mi][nj][rr] * scale);
            }
}

// ---------------- encoder GEMM: yenc += ybf(512x32768) @ encT^T (split-K 32) ----------
__global__ __launch_bounds__(256) void gemm_enc_bt(const unsigned short* __restrict__ A,
                                                   const unsigned short* __restrict__ Bt,
                                                   float* __restrict__ C) {
    int n0 = blockIdx.x * 128, m0 = blockIdx.y * 128;
    long kbase = (long)blockIdx.z * 1024;
    __shared__ unsigned short As[128][36], Bs[128][36];
    f32x4 acc[4][4] = {};
    bt_mainloop(A + (size_t)m0 * NN + kbase, NN,
                Bt + (size_t)n0 * NN + kbase, NN, 32, As, Bs, acc);
    int tid = threadIdx.x, lane = tid & 63, w = tid >> 6;
    int rowoff = (w >> 1) * 64, coloff = (w & 1) * 64;
    int r4 = (lane >> 4) * 4, cc = lane & 15;
    #pragma unroll
    for (int mi = 0; mi < 4; mi++)
        #pragma unroll
        for (int nj = 0; nj < 4; nj++)
            #pragma unroll
            for (int rr = 0; rr < 4; rr++) {
                int row = m0 + rowoff + mi * 16 + r4 + rr;
                int col = n0 + coloff + nj * 16 + cc;
                atomicAdd(&C[(size_t)row * DD + col], acc[mi][nj][rr]);
            }
}

// ---------------- readout: out = vb @ WroT^T, fp32 out ----------------
__global__ __launch_bounds__(256) void gemm_ro_bt(const unsigned short* __restrict__ A,
                                                  const unsigned short* __restrict__ Wt,
                                                  float* __restrict__ out) {
    int n0 = blockIdx.x * 128, m0 = blockIdx.y * 128;
    __shared__ unsigned short As[128][36], Bs[128][36];
    f32x4 acc[4][4] = {};
    bt_mainloop(A + (size_t)m0 * DD, DD, Wt + (size_t)n0 * DD, DD, 8, As, Bs, acc);
    int tid = threadIdx.x, lane = tid & 63, w = tid >> 6;
    int rowoff = (w >> 1) * 64, coloff = (w & 1) * 64;
    int r4 = (lane >> 4) * 4, cc = lane & 15;
    #pragma unroll
    for (int mi = 0; mi < 4; mi++)
        #pragma unroll
        for (int nj = 0; nj < 4; nj++)
            #pragma unroll
            for (int rr = 0; rr < 4; rr++) {
                int m = m0 + rowoff + mi * 16 + r4 + rr;
                int col = n0 + coloff + nj * 16 + cc;
                out[(size_t)m * VV + col] = acc[mi][nj][rr];
            }
}

// ---------------- causal softmax per (b,h,t) + mean over h -> am (B,T,T) ----------------
__global__ __launch_bounds__(256) void softmax_mean_k(const float* __restrict__ sc,
                                                      float* __restrict__ am) {
    int bt = blockIdx.x;
    int b = bt >> 8, t = bt & 255;
    int s = threadIdx.x;
    float acc = 0.0f;
    for (int h = 0; h < HH; h++) {
        const float* row = sc + (((size_t)(b * HH + h)) * TT + t) * TT;
        float val = (s <= t) ? row[s] : -1e30f;
        float mx = block_max(val);
        float e = (s <= t) ? expf(val - mx) : 0.0f;
        float sum = block_sum(e);
        acc += e / sum;
    }
    am[((size_t)b * TT + t) * TT + s] = acc * 0.25f;
}

// ---------------- fp32 NN GEMM — used only for a = am @ v ----------------
__global__ __launch_bounds__(256) void gemm_nn_k(const float* __restrict__ A,
                                                 const float* __restrict__ B,
                                                 float* __restrict__ C,
                                                 int M, int N, int K,
                                                 long lda, long ldb, long ldc,
                                                 long sAz, long sBz, long sCz) {
    int batch = blockIdx.z;
    A += (size_t)batch * sAz;
    B += (size_t)batch * sBz;
    C += (size_t)batch * sCz;
    int m0 = blockIdx.y * 64, n0 = blockIdx.x * 64;
    __shared__ float As[16][68];
    __shared__ float Bs[16][64];
    int tid = threadIdx.x;
    int tx = tid & 15, ty = tid >> 4;
    int ar = tid >> 2, ac = (tid & 3) * 4;
    int br = tid >> 4, bc = (tid & 15) * 4;
    float acc[4][4] = {};
    for (int k0 = 0; k0 < K; k0 += 16) {
        float4 av = *(const float4*)(A + (size_t)(m0 + ar) * lda + k0 + ac);
        float4 bv = *(const float4*)(B + (size_t)(k0 + br) * ldb + n0 + bc);
        As[ac + 0][ar] = av.x; As[ac + 1][ar] = av.y;
        As[ac + 2][ar] = av.z; As[ac + 3][ar] = av.w;
        *(float4*)&Bs[br][bc] = bv;
        __syncthreads();
        #pragma unroll
        for (int k = 0; k < 16; k++) {
            float4 a4 = *(const float4*)&As[k][ty * 4];
            float4 b4 = *(const float4*)&Bs[k][tx * 4];
            float aa[4] = {a4.x, a4.y, a4.z, a4.w};
            float bb[4] = {b4.x, b4.y, b4.z, b4.w};
            #pragma unroll
            for (int i = 0; i < 4; i++)
                #pragma unroll
                for (int j = 0; j < 4; j++)
                    acc[i][j] = fmaf(aa[i], bb[j], acc[i][j]);
        }
        __syncthreads();
    }
    #pragma unroll
    for (int i = 0; i < 4; i++) {
        int m = m0 + ty * 4 + i;
        #pragma unroll
        for (int j = 0; j < 4; j++) {
            int col = n0 + tx * 4 + j;
            C[(size_t)m * ldc + col] = acc[i][j];
        }
    }
}

// ---------------- launch ----------------
extern "C" void kernel_launch(void* const* d_in, const int* in_sizes, int n_in,
                              void* d_out, int out_size, void* d_ws, size_t ws_size,
                              hipStream_t stream) {
    const int*   idx  = (const int*)d_in[0];
    const float* wte  = (const float*)d_in[1];
    const float* enc  = (const float*)d_in[2];
    const float* Wx   = (const float*)d_in[3];
    const float* Wy   = (const float*)d_in[4];
    const float* Wro  = (const float*)d_in[5];
    float* out = (float*)d_out;

    // float region (1,048,576 floats = 4 MB)
    float* ws   = (float*)d_ws;
    float* v    = ws;                  // 131072
    float* sc   = v    + 131072;       // 524288
    float* am   = sc   + 524288;       // 131072
    float* a    = am   + 131072;       // 131072
    float* yenc = a    + 131072;       // 131072
    // short region
    unsigned short* sbase = (unsigned short*)(yenc + 131072);
    unsigned short* vb   = sbase;                 // 131072
    unsigned short* lAb  = vb   + 131072;         // 131072
    unsigned short* xb   = lAb  + 131072;         // 16777216 (B,H,T,n); WroT aliases at end
    unsigned short* xrb  = xb   + 16777216;       // 16777216 (B,H,T,n); ybf aliases
    unsigned short* WxT  = xrb  + 16777216;       // 8388608  [h][8192][256]
    unsigned short* WyT  = WxT  + 8388608;        // 8388608
    unsigned short* encT = WyT  + 8388608;        // 8388608  [256][32768]
    unsigned short* ybf  = xrb;                   // alias: xrb dead after scores
    unsigned short* WroT = xb;                    // alias: xb dead after last y-GEMM

    // pre-pass: weight transpose+convert (once per launch, amortized over 6 layers)
    tconv_k<<<dim3(nn / 64, DD / 64, HH), 256, 0, stream>>>(Wx, WxT, DD, nn,
        (long)DD * nn, (long)nn * DD);
    tconv_k<<<dim3(DD / 64, NN / 64, 1), 256, 0, stream>>>(enc, encT, NN, DD, 0L, 0L);
    tconv_k<<<dim3(nn / 64, DD / 64, HH), 256, 0, stream>>>(Wy, WyT, DD, nn,
        (long)DD * nn, (long)nn * DD);

    // v = ln(wte[idx]) (+ bf16)
    embed_ln_k<<<BB * TT, 256, 0, stream>>>(idx, wte, v, vb);

    for (int l = 0; l < L_LAYERS; l++) {
        // xb = bf16(relu(vb @ WxT[h])), xrb = rope(xb) — fused
        gemm_head_bt<<<dim3(nn / 128, (BB * TT) / 128, HH), 256, 0, stream>>>(
            vb, WxT, xb, nullptr, xrb, 0);

        // sc = scale * xrb @ xrb^T (split-K 16, causal tiles)
        hipMemsetAsync(sc, 0, (size_t)524288 * sizeof(float), stream);
        scores_bt<<<dim3(3, 16, BB * HH), 256, 0, stream>>>(xrb, sc);

        // softmax (causal) + mean over heads
        softmax_mean_k<<<BB * TT, 256, 0, stream>>>(sc, am);

        // a = am @ v (per b), fp32
        gemm_nn_k<<<dim3(DD / 64, TT / 64, BB), 256, 0, stream>>>(
            am, v, a, TT, DD, TT,
            (long)TT, (long)DD, (long)DD,
            (long)TT * TT, (long)TT * DD, (long)TT * DD);

        // lAb = bf16(ln(a))
        ln_rows_k<<<BB * TT, 256, 0, stream>>>(a, lAb);

        // ybf = bf16(relu(lAb @ WyT[h]) * xb)   (ybf aliases xrb)
        gemm_head_bt<<<dim3(nn / 128, (BB * TT) / 128, HH), 256, 0, stream>>>(
            lAb, WyT, nullptr, xb, ybf, 1);

        // yenc = ybf @ enc (split-K 32)
        hipMemsetAsync(yenc, 0, (size_t)131072 * sizeof(float), stream);
        gemm_enc_bt<<<dim3(2, 4, 32), 256, 0, stream>>>(ybf, encT, yenc);

        // v = ln(v + ln(yenc)) (+ bf16)
        add_ln_ln_k<<<BB * TT, 256, 0, stream>>>(v, yenc, vb);
    }

    // WroT = transpose+bf16(Wro) into xb region (xb dead now)
    tconv_k<<<dim3(VV / 64, DD / 64, 1), 256, 0, stream>>>(Wro, WroT, DD, VV, 0L, 0L);

    // out = vb @ WroT^T (fp32 out)
    gemm_ro_bt<<<dim3(VV / 128, (BB * TT) / 128, 1), 256, 0, stream>>>(vb, WroT, out);
}